// Round 1
// baseline (259.411 us; speedup 1.0000x reference)
//
#include <hip/hip_runtime.h>
#include <hip/hip_bf16.h>
#include <math.h>

namespace {

constexpr int kB = 32;
constexpr int kS = 2048;
constexpr int kI = 32;
constexpr int kW = 20;
constexpr int kH = 128;
constexpr int kNwin = kS - kW + 1;   // 2029
constexpr int kT = kS - 2 * kW;      // 2008
constexpr float kEps = 1e-5f;

__device__ __forceinline__ float gelu_exact(float v) {
    return 0.5f * v * (1.0f + erff(v * 0.70710678118654752440f));
}

// ---------------- encoder: h = win @ W_enc + b ; LN ; GELU ----------------
constexpr int ETT = 128;             // t-rows per block
constexpr int XSR = ETT + kW - 1;    // 147 x-rows staged
constexpr int XST = 33;              // padded LDS row stride (floats)

__global__ __launch_bounds__(256, 2)
void enc_kernel(const float* __restrict__ x, const float* __restrict__ Wenc,
                const float* __restrict__ benc, const float* __restrict__ gma,
                const float* __restrict__ bta, float* __restrict__ enc)
{
    __shared__ float xs[XSR * XST];   // 4851 floats (~19.4 KB)
    __shared__ float wb[32 * kH];     // 4096 floats (16 KB)

    const int tid = threadIdx.x;
    const int b   = blockIdx.y;
    const int t0  = blockIdx.x * ETT;

    // stage x rows [t0, t0+147) (clamped) — window row t, element k is xs[(t-t0+k/32)*XST + k%32]
    const float4* x4 = reinterpret_cast<const float4*>(x + (size_t)b * kS * kI);
    for (int i = tid; i < XSR * 8; i += 256) {
        int r = i >> 3, c4 = i & 7;
        int gr = t0 + r; if (gr > kS - 1) gr = kS - 1;
        float4 v = x4[gr * 8 + c4];
        float* dst = &xs[r * XST + c4 * 4];
        dst[0] = v.x; dst[1] = v.y; dst[2] = v.z; dst[3] = v.w;
    }

    const int rt = tid >> 4;   // rows rt*8 .. rt*8+7   (16 x 8 = 128 rows)
    const int rh = tid & 15;   // cols rh*8 .. rh*8+7   (16 x 8 = 128 cols)

    float acc[8][8];
    #pragma unroll
    for (int i = 0; i < 8; ++i)
        #pragma unroll
        for (int j = 0; j < 8; ++j) acc[i][j] = 0.0f;

    for (int kc = 0; kc < 20; ++kc) {   // K = 640 in chunks of 32
        __syncthreads();
        {
            const float4* w4 = reinterpret_cast<const float4*>(Wenc + kc * 32 * kH);
            float4* wb4 = reinterpret_cast<float4*>(wb);
            #pragma unroll
            for (int i = 0; i < 4; ++i) wb4[tid + 256 * i] = w4[tid + 256 * i];
        }
        __syncthreads();
        // within chunk kc, k = kc*32+kk -> x row offset = kc, col = kk
        const int abase = (rt * 8 + kc) * XST;
        #pragma unroll 4
        for (int kk = 0; kk < 32; ++kk) {
            float a[8];
            #pragma unroll
            for (int i = 0; i < 8; ++i) a[i] = xs[abase + i * XST + kk];
            const float4 w0 = *reinterpret_cast<const float4*>(&wb[kk * kH + rh * 8]);
            const float4 w1 = *reinterpret_cast<const float4*>(&wb[kk * kH + rh * 8 + 4]);
            const float wv[8] = {w0.x, w0.y, w0.z, w0.w, w1.x, w1.y, w1.z, w1.w};
            #pragma unroll
            for (int i = 0; i < 8; ++i)
                #pragma unroll
                for (int j = 0; j < 8; ++j)
                    acc[i][j] = fmaf(a[i], wv[j], acc[i][j]);
        }
    }

    float bv[8], gv[8], btv[8];
    #pragma unroll
    for (int j = 0; j < 8; ++j) {
        bv[j]  = benc[rh * 8 + j];
        gv[j]  = gma[rh * 8 + j];
        btv[j] = bta[rh * 8 + j];
    }

    // LN (row stats across the 16 rh-lanes of this wave) + GELU + store
    #pragma unroll
    for (int i = 0; i < 8; ++i) {
        const int t = t0 + rt * 8 + i;
        float h[8];
        float s = 0.0f;
        #pragma unroll
        for (int j = 0; j < 8; ++j) { h[j] = acc[i][j] + bv[j]; s += h[j]; }
        #pragma unroll
        for (int m = 1; m < 16; m <<= 1) s += __shfl_xor(s, m, 64);
        const float mu = s * (1.0f / 128.0f);
        float s2 = 0.0f;
        #pragma unroll
        for (int j = 0; j < 8; ++j) { h[j] -= mu; s2 += h[j] * h[j]; }
        #pragma unroll
        for (int m = 1; m < 16; m <<= 1) s2 += __shfl_xor(s2, m, 64);
        const float rstd = 1.0f / sqrtf(s2 * (1.0f / 128.0f) + kEps);
        float o[8];
        #pragma unroll
        for (int j = 0; j < 8; ++j) o[j] = gelu_exact(h[j] * rstd * gv[j] + btv[j]);
        if (t < kNwin) {
            float4* dst = reinterpret_cast<float4*>(enc + ((size_t)(b * kS + t)) * kH + rh * 8);
            dst[0] = make_float4(o[0], o[1], o[2], o[3]);
            dst[1] = make_float4(o[4], o[5], o[6], o[7]);
        }
    }
}

// ---------------- comparator MLP: 256 -> 128 -> 64 -> 1, sigmoid ----------------
constexpr int CTT = 64;              // t-rows per block
constexpr int EST = 132;             // padded stride for enc/z1 in LDS

__global__ __launch_bounds__(256, 2)
void cmp_kernel(const float* __restrict__ enc,
                const float* __restrict__ W1, const float* __restrict__ b1,
                const float* __restrict__ W2, const float* __restrict__ b2,
                const float* __restrict__ W3, const float* __restrict__ b3,
                float* __restrict__ out)
{
    __shared__ float pool[15360];     // 61.4 KB, phase-managed
    const int tid = threadIdx.x;
    const int b   = blockIdx.y;
    const int t0  = blockIdx.x * CTT;

    float* encb = pool;               // phase 1: 84 x 132 = 11088
    float* wb   = pool + 11088;       // phase 1: 32 x 128 = 4096

    {   // stage enc rows [t0, t0+84) (clamped to valid 2028)
        const float4* e4 = reinterpret_cast<const float4*>(enc);
        for (int i = tid; i < 84 * 32; i += 256) {
            int r = i >> 5, c4 = i & 31;
            int gr = t0 + r; if (gr > kNwin - 1) gr = kNwin - 1;
            float4 v = e4[((size_t)(b * kS + gr)) * 32 + c4];
            float* dst = &encb[r * EST + c4 * 4];
            dst[0] = v.x; dst[1] = v.y; dst[2] = v.z; dst[3] = v.w;
        }
    }

    const int rt = tid >> 4;   // 0..15
    const int rh = tid & 15;   // 0..15

    // ---- layer 1: (64 x 256) @ W1(256 x 128); A[t][k] = enc[t + (k<128?0:20)][k%128]
    float acc1[4][8];
    #pragma unroll
    for (int i = 0; i < 4; ++i)
        #pragma unroll
        for (int j = 0; j < 8; ++j) acc1[i][j] = 0.0f;

    for (int kc = 0; kc < 8; ++kc) {
        __syncthreads();
        {
            const float4* w4 = reinterpret_cast<const float4*>(W1 + kc * 32 * kH);
            float4* wb4 = reinterpret_cast<float4*>(wb);
            #pragma unroll
            for (int i = 0; i < 4; ++i) wb4[tid + 256 * i] = w4[tid + 256 * i];
        }
        __syncthreads();
        const int rbase = (kc < 4) ? 0 : kW;
        const int cbase = (kc & 3) * 32;
        #pragma unroll 4
        for (int kk = 0; kk < 32; ++kk) {
            float a[4];
            #pragma unroll
            for (int i = 0; i < 4; ++i) a[i] = encb[(rt * 4 + i + rbase) * EST + cbase + kk];
            const float4 w0 = *reinterpret_cast<const float4*>(&wb[kk * kH + rh * 8]);
            const float4 w1v = *reinterpret_cast<const float4*>(&wb[kk * kH + rh * 8 + 4]);
            const float wv[8] = {w0.x, w0.y, w0.z, w0.w, w1v.x, w1v.y, w1v.z, w1v.w};
            #pragma unroll
            for (int i = 0; i < 4; ++i)
                #pragma unroll
                for (int j = 0; j < 8; ++j)
                    acc1[i][j] = fmaf(a[i], wv[j], acc1[i][j]);
        }
    }
    __syncthreads();   // everyone done reading encb
    {
        float b1v[8];
        #pragma unroll
        for (int j = 0; j < 8; ++j) b1v[j] = b1[rh * 8 + j];
        #pragma unroll
        for (int i = 0; i < 4; ++i)
            #pragma unroll
            for (int j = 0; j < 8; ++j)
                pool[(rt * 4 + i) * EST + rh * 8 + j] = gelu_exact(acc1[i][j] + b1v[j]);
    }

    float* z1b = pool;             // 64 x 132 = 8448
    float* z2b = pool + 8448;      // 64 x 68  = 4352 (ends 12800)
    float* w2b = pool + 12800;     // 32 x 64  = 2048 (ends 14848)

    // ---- layer 2: (64 x 128) @ W2(128 x 64)
    float acc2[4][4];
    #pragma unroll
    for (int i = 0; i < 4; ++i)
        #pragma unroll
        for (int j = 0; j < 4; ++j) acc2[i][j] = 0.0f;

    for (int kc = 0; kc < 4; ++kc) {
        __syncthreads();
        {
            const float4* w4 = reinterpret_cast<const float4*>(W2 + kc * 32 * 64);
            float4* w2b4 = reinterpret_cast<float4*>(w2b);
            #pragma unroll
            for (int i = 0; i < 2; ++i) w2b4[tid + 256 * i] = w4[tid + 256 * i];
        }
        __syncthreads();
        #pragma unroll 4
        for (int kk = 0; kk < 32; ++kk) {
            float a[4];
            #pragma unroll
            for (int i = 0; i < 4; ++i) a[i] = z1b[(rt * 4 + i) * EST + kc * 32 + kk];
            const float4 w0 = *reinterpret_cast<const float4*>(&w2b[kk * 64 + rh * 4]);
            const float wv[4] = {w0.x, w0.y, w0.z, w0.w};
            #pragma unroll
            for (int i = 0; i < 4; ++i)
                #pragma unroll
                for (int j = 0; j < 4; ++j)
                    acc2[i][j] = fmaf(a[i], wv[j], acc2[i][j]);
        }
    }
    __syncthreads();
    {
        float b2v[4];
        #pragma unroll
        for (int j = 0; j < 4; ++j) b2v[j] = b2[rh * 4 + j];
        #pragma unroll
        for (int i = 0; i < 4; ++i)
            #pragma unroll
            for (int j = 0; j < 4; ++j)
                z2b[(rt * 4 + i) * 68 + rh * 4 + j] = gelu_exact(acc2[i][j] + b2v[j]);
    }
    __syncthreads();

    // ---- layer 3: (64 x 64) @ W3(64 x 1) + sigmoid, write both outputs
    {
        const int row = tid >> 2, q = tid & 3;
        float s = 0.0f;
        #pragma unroll
        for (int hh = 0; hh < 16; ++hh) s += z2b[row * 68 + q * 16 + hh] * W3[q * 16 + hh];
        s += __shfl_xor(s, 1, 64);
        s += __shfl_xor(s, 2, 64);
        if (q == 0) {
            const int t = t0 + row;
            if (t < kT) {
                const float logit = s + b3[0];
                const float p = 1.0f / (1.0f + expf(-logit));
                out[(size_t)b * kS + t + kW] = p;
                out[(size_t)kB * kS + (size_t)b * kS + t + kW] = (p > 0.5f) ? 1.0f : 0.0f;
            }
        }
    }
}

}  // namespace

extern "C" void kernel_launch(void* const* d_in, const int* in_sizes, int n_in,
                              void* d_out, int out_size, void* d_ws, size_t ws_size,
                              hipStream_t stream)
{
    const float* x    = (const float*)d_in[0];
    const float* Wenc = (const float*)d_in[1];
    const float* benc = (const float*)d_in[2];
    const float* gma  = (const float*)d_in[3];
    const float* bta  = (const float*)d_in[4];
    const float* W1   = (const float*)d_in[5];
    const float* b1   = (const float*)d_in[6];
    const float* W2   = (const float*)d_in[7];
    const float* b2   = (const float*)d_in[8];
    const float* W3   = (const float*)d_in[9];
    const float* b3   = (const float*)d_in[10];
    float* out = (float*)d_out;
    float* enc = (float*)d_ws;   // 32 * 2048 * 128 floats = 33.5 MB scratch

    // zero both output planes (pad columns must be 0; d_out is poisoned)
    hipMemsetAsync(d_out, 0, (size_t)out_size * sizeof(float), stream);

    // encoder: grid covers 16*128 = 2048 >= nwin t-rows per batch
    enc_kernel<<<dim3(16, kB), 256, 0, stream>>>(x, Wenc, benc, gma, bta, enc);
    // comparator: 32*64 = 2048 >= T t-rows per batch
    cmp_kernel<<<dim3(32, kB), 256, 0, stream>>>(enc, W1, b1, W2, b2, W3, b3, out);
}